// Round 16
// baseline (351.923 us; speedup 1.0000x reference)
//
#include <hip/hip_runtime.h>
#include <hip/hip_bf16.h>
#include <hip/hip_fp16.h>
#include <math.h>

#define N_NODES 50000
#define N_EDGES 800000
#define E_TOT   850000   // N_EDGES + N_NODES self-loops
#define SCAN_B  1024

typedef __hip_bfloat16 bf16;
typedef __attribute__((ext_vector_type(8))) short short8v;   // 8 bf16 (4 VGPR)
typedef __attribute__((ext_vector_type(4))) float float4v;   // MFMA acc

static __device__ __forceinline__ float u2f(unsigned short u) {
    return __uint_as_float(((unsigned int)u) << 16);
}
static __device__ __forceinline__ unsigned short f2u(float f) {   // RNE f32->bf16
    unsigned int u = __float_as_uint(f);
    return (unsigned short)((u + 0x7FFFu + ((u >> 16) & 1u)) >> 16);
}
static __device__ __forceinline__ float ldr(const void* p, int i, bool bf) {
    return bf ? u2f(((const unsigned short*)p)[i]) : ((const float*)p)[i];
}

// ------------------ init: zero scratch + dtype detection -------------------
__global__ void k_init(const unsigned int* __restrict__ x32,
                       const unsigned int* __restrict__ ei32,
                       int* __restrict__ zero_base, int nzero,
                       int* __restrict__ flags) {
    int i = blockIdx.x * 256 + threadIdx.x;
    if (i < nzero) zero_base[i] = 0;
    if (blockIdx.x == 0) {
        __shared__ int c1, c2;
        if (threadIdx.x == 0) { c1 = 0; c2 = 0; }
        __syncthreads();
        unsigned int e = (x32[threadIdx.x] >> 7) & 0xFF;
        if (e >= 90 && e <= 140) atomicAdd(&c1, 1);
        if (threadIdx.x < 64 && ei32[2 * threadIdx.x + 1] == 0) atomicAdd(&c2, 1);
        __syncthreads();
        if (threadIdx.x == 0) {
            flags[0] = (c1 >= 128) ? 1 : 0;   // float inputs are bf16
            flags[1] = (c2 >= 48) ? 1 : 0;    // edge_index is int64
        }
    }
}

// ------------------------------ CSR build ---------------------------------
__global__ void k_hist(const int* __restrict__ flags, const void* __restrict__ ei,
                       int* __restrict__ counts) {
    int i = blockIdx.x * blockDim.x + threadIdx.x;
    if (i >= E_TOT) return;
    int d;
    if (i < N_EDGES)
        d = flags[1] ? (int)((const long long*)ei)[N_EDGES + i]
                     : ((const int*)ei)[N_EDGES + i];
    else
        d = i - N_EDGES;
    atomicAdd(&counts[d], 1);
}

__global__ void k_scan1(const int* __restrict__ counts, int* __restrict__ scanned,
                        int* __restrict__ partial, int n) {
    __shared__ int sh[SCAN_B];
    int i = blockIdx.x * SCAN_B + threadIdx.x;
    sh[threadIdx.x] = (i < n) ? counts[i] : 0;
    __syncthreads();
    for (int off = 1; off < SCAN_B; off <<= 1) {
        int t = (threadIdx.x >= off) ? sh[threadIdx.x - off] : 0;
        __syncthreads();
        sh[threadIdx.x] += t;
        __syncthreads();
    }
    if (i < n) scanned[i] = sh[threadIdx.x];
    if (threadIdx.x == SCAN_B - 1) partial[blockIdx.x] = sh[SCAN_B - 1];
}

// rowptr/cursor; per-block prefix of `partial` computed inline (j is
// block-uniform: 256-thread blocks align inside 1024-node scan tiles).
__global__ void k_scan3(const int* __restrict__ counts, const int* __restrict__ scanned,
                        const int* __restrict__ partial, int* __restrict__ rowptr,
                        int* __restrict__ cursor, int n) {
    __shared__ int base_sh;
    if (threadIdx.x == 0) {
        const int jmax = (blockIdx.x * 256) / SCAN_B;
        int acc = 0;
        for (int b = 0; b < jmax; b++) acc += partial[b];
        base_sh = acc;
    }
    __syncthreads();
    int i = blockIdx.x * 256 + threadIdx.x;
    if (i >= n) return;
    int incl = scanned[i] + base_sh;
    rowptr[i + 1] = incl;
    cursor[i]     = incl - counts[i];
    if (i == 0) rowptr[0] = 0;
}

__global__ void k_scatter(const int* __restrict__ flags, const void* __restrict__ ei,
                          int* __restrict__ cursor, int* __restrict__ csr_src) {
    int i = blockIdx.x * blockDim.x + threadIdx.x;
    if (i >= E_TOT) return;
    int s, d;
    if (i < N_EDGES) {
        if (flags[1]) {
            s = (int)((const long long*)ei)[i];
            d = (int)((const long long*)ei)[N_EDGES + i];
        } else {
            s = ((const int*)ei)[i];
            d = ((const int*)ei)[N_EDGES + i];
        }
    } else {
        s = d = i - N_EDGES;
    }
    int pos = atomicAdd(&cursor[d], 1);
    csr_src[pos] = s;
}

// --------------- canonicalization: x, weights, small params ----------------
struct PrepArgs { const void* src[13]; int off[13]; int len[13]; };

__global__ void k_prep_misc(const int* __restrict__ flags,
                            const void* __restrict__ x, bf16* __restrict__ xb, int n4,
                            const void* __restrict__ W1, const void* __restrict__ W2,
                            const void* __restrict__ W3,
                            bf16* __restrict__ Wt1, bf16* __restrict__ Wt2,
                            bf16* __restrict__ Wt3,
                            PrepArgs a, float* __restrict__ par) {
    const bool bf = flags[0] != 0;
    const int b = blockIdx.x;
    if (b < 320) {
        int i = b * 256 + threadIdx.x;
        if (i < 32768) {                       // W1 [128][256] -> Wt1 [256][128]
            int k = i >> 8, c = i & 255;
            Wt1[c * 128 + k] = __float2bfloat16(ldr(W1, i, bf));
        } else if (i < 65536) {                // W2 [256][128] -> Wt2 [128][256]
            int j = i - 32768, k = j >> 7, c = j & 127;
            Wt2[c * 256 + k] = __float2bfloat16(ldr(W2, j, bf));
        } else if (i < 81920) {                // W3 [128][128] -> Wt3 [128][128]
            int j = i - 65536, k = j >> 7, c = j & 127;
            Wt3[c * 128 + k] = __float2bfloat16(ldr(W3, j, bf));
        }
    } else if (b < 333) {
        int seg = b - 320;                     // 13 segments
        for (int i = threadIdx.x; i < a.len[seg]; i += blockDim.x)
            par[a.off[seg] + i] = ldr(a.src[seg], i, bf);
    } else {
        int i = (b - 333) * 256 + threadIdx.x; // x -> bf16 (vec4)
        if (i < n4) {
            if (bf) {
                ((ushort4*)xb)[i] = ((const ushort4*)x)[i];
            } else {
                float4 f = ((const float4*)x)[i];
                ushort4 u;
                u.x = f2u(f.x); u.y = f2u(f.y); u.z = f2u(f.z); u.w = f2u(f.w);
                ((ushort4*)xb)[i] = u;
            }
        }
    }
}

// ------------- MFMA GEMM (swapped operands) + fused attention dots ---------
// A [M][K] bf16; Wt [NT][K] bf16; xp [M][NT] f16.
// When NSG==H each slice-group is the sole writer of its head's dots ->
// plain stores instead of atomics (asr buffers pre-zeroed anyway).
template<int K, int NT, int SPW, int H>
__global__ __launch_bounds__(256) void k_gemm_mfma2(const bf16* __restrict__ A,
                                                    const bf16* __restrict__ Wt,
                                                    unsigned short* __restrict__ xp,
                                                    const float* __restrict__ att_s,
                                                    const float* __restrict__ att_d,
                                                    float* __restrict__ asr,
                                                    float* __restrict__ adst) {
    constexpr int KF     = K / 32;
    constexpr int NSG    = NT / (16 * SPW);
    constexpr int NTILES = N_NODES / 16;
    constexpr int C      = NT / H;
    const int l    = threadIdx.x & 63;
    const int wid  = blockIdx.x * 4 + (threadIdx.x >> 6);
    const int sg   = wid % NSG;
    const int wpg  = (gridDim.x * 4) / NSG;
    const int t0   = wid / NSG;
    const int r16  = l & 15;
    const int kgrp = (l >> 4) * 8;
    const int head = (sg * SPW * 16) / C;

    short8v b[SPW][KF];
    float as_r[SPW][4], ad_r[SPW][4];
    #pragma unroll
    for (int s = 0; s < SPW; s++) {
        const int cs  = (sg * SPW + s) * 16;
        const int col = cs + r16;
        #pragma unroll
        for (int kf = 0; kf < KF; kf++)
            b[s][kf] = *(const short8v*)(Wt + (size_t)col * K + kf * 32 + kgrp);
        #pragma unroll
        for (int r = 0; r < 4; r++) {
            const int ch = cs + (l >> 4) * 4 + r;
            as_r[s][r] = att_s[ch];
            ad_r[s][r] = att_d[ch];
        }
    }

    for (int t = t0; t < NTILES; t += wpg) {
        const int m0 = t * 16;
        short8v a[KF];
        #pragma unroll
        for (int kf = 0; kf < KF; kf++)
            a[kf] = *(const short8v*)(A + (size_t)(m0 + r16) * K + kf * 32 + kgrp);
        float4v acc[SPW] = {};
        #pragma unroll
        for (int kf = 0; kf < KF; kf++)
            #pragma unroll
            for (int s = 0; s < SPW; s++)
                acc[s] = __builtin_amdgcn_mfma_f32_16x16x32_bf16(b[s][kf], a[kf], acc[s], 0, 0, 0);

        float pa = 0.f, pd = 0.f;
        #pragma unroll
        for (int s = 0; s < SPW; s++)
            #pragma unroll
            for (int r = 0; r < 4; r++) {
                pa = fmaf(acc[s][r], as_r[s][r], pa);
                pd = fmaf(acc[s][r], ad_r[s][r], pd);
            }
        pa += __shfl_xor(pa, 16); pa += __shfl_xor(pa, 32);
        pd += __shfl_xor(pd, 16); pd += __shfl_xor(pd, 32);
        if (l < 16) {
            if constexpr (NSG == H) {
                asr [(size_t)(m0 + l) * H + head] = pa;
                adst[(size_t)(m0 + l) * H + head] = pd;
            } else {
                atomicAdd(&asr [(size_t)(m0 + l) * H + head], pa);
                atomicAdd(&adst[(size_t)(m0 + l) * H + head], pd);
            }
        }

        const int node = m0 + r16;
        #pragma unroll
        for (int s = 0; s < SPW; s++) {
            const int ch = (sg * SPW + s) * 16 + (l >> 4) * 4;
            uint2 o;
            o.x = (unsigned int)__half_as_ushort(__float2half(acc[s][0])) |
                  ((unsigned int)__half_as_ushort(__float2half(acc[s][1])) << 16);
            o.y = (unsigned int)__half_as_ushort(__float2half(acc[s][2])) |
                  ((unsigned int)__half_as_ushort(__float2half(acc[s][3])) << 16);
            *(uint2*)(xp + (size_t)node * NT + ch) = o;
        }
    }
}

// ---- SINGLE-PASS edge-softmax + aggregation + bias (+ LayerNorm + ELU) ----
// Full chunks (exactly LPH edges) run a COMPILE-TIME-count group loop so the
// scheduler can hoist group g+1's gathers above group g's FMAs (cross-group
// MLP); runtime-size tail chunk handles the remainder. Defer-max single pass;
// ONE node per full wave; v_fma_mix unpack; 32-bit offsets; f16 xp.
template<int CT, int H, bool LAST>
__global__ __launch_bounds__(256) void k_agg9(const int* __restrict__ flags,
                                              const unsigned short* __restrict__ xp,
                                              const float* __restrict__ asr,
                                              const float* __restrict__ adst,
                                              const int* __restrict__ rowptr,
                                              const int* __restrict__ csr_src,
                                              const float* __restrict__ bias,
                                              const float* __restrict__ gamma,
                                              const float* __restrict__ beta,
                                              void* __restrict__ outv) {
    constexpr int V   = CT / 64;      // channels per lane (4 or 2)
    constexpr int C   = CT / H;
    constexpr int LPH = C / V;        // lanes per head group (16/32/64)
    constexpr int ND  = V / 2;        // dwords gathered per lane (2 or 1)
    constexpr int STR = CT / 2;       // xp row stride in dwords (pow2)
    constexpr int G   = (ND == 2) ? 4 : 8;   // gather group depth
    const int l     = threadIdx.x & 63;
    const int w     = threadIdx.x >> 6;
    const int hd    = l / LPH;
    const int slot  = l & (LPH - 1);
    const int lbase = hd * LPH;
    const unsigned int coff = ND * l;

    float bv[V], gv[V], bev[V];
    #pragma unroll
    for (int v = 0; v < V; v++) bv[v] = bias[V * l + v];
    if constexpr (!LAST) {
        #pragma unroll
        for (int v = 0; v < V; v++) {
            gv[v]  = gamma[V * l + v];
            bev[v] = beta [V * l + v];
        }
    }
    const unsigned int* xpd = (const unsigned int*)xp;

    const int n = blockIdx.x * 4 + w;
    if (n >= N_NODES) return;
    const int b0 = rowptr[n], b1 = rowptr[n + 1];
    const int deg = b1 - b0;
    const float ad = adst[n * H + hd];

    float ssum = 0.f;
    float acc[V];
    #pragma unroll
    for (int v = 0; v < V; v++) acc[v] = 0.f;

    // group body (shared by full-chunk and tail paths)
    auto do_group = [&](int sn_l, float p_l, int eb) {
        unsigned int offs[G]; float ps[G];
        #pragma unroll
        for (int g = 0; g < G; g++) {
            int sn = __shfl(sn_l, lbase + eb + g);
            ps[g]  = __shfl(p_l,  lbase + eb + g);
            offs[g] = (unsigned int)sn * STR + coff;       // 32-bit offsets
        }
        unsigned int d[G][ND];
        #pragma unroll
        for (int g = 0; g < G; g++) {
            if constexpr (ND == 2)
                *(uint2*)d[g] = *(const uint2*)(xpd + offs[g]);
            else
                d[g][0] = xpd[offs[g]];
        }
        #pragma unroll
        for (int g = 0; g < G; g++) {
            ssum += ps[g];
            #pragma unroll
            for (int k = 0; k < ND; k++) {
                __half2 h2 = *(__half2*)&d[g][k];          // -> v_fma_mix_f32
                acc[2 * k]     = fmaf(ps[g], __low2float(h2),  acc[2 * k]);
                acc[2 * k + 1] = fmaf(ps[g], __high2float(h2), acc[2 * k + 1]);
            }
        }
    };

    int cbase = 0;
    // full chunks: all slots active, compile-time group count (LPH/G)
    for (; cbase + LPH <= deg; cbase += LPH) {
        int sn_l = csr_src[b0 + cbase + slot];
        float e = asr[(unsigned)(sn_l * H + hd)] + ad;
        e = e > 0.f ? e : 0.2f * e;
        float p_l = __expf(fminf(e, 80.f));
        #pragma unroll
        for (int eb = 0; eb < LPH; eb += G)
            do_group(sn_l, p_l, eb);
    }
    // tail chunk: runtime count, zero-padded alpha
    if (cbase < deg) {
        const int nn = deg - cbase;
        int   sn_l = csr_src[b0];        // pad lanes re-fetch a hot row
        float p_l  = 0.f;
        if (slot < nn) {
            sn_l = csr_src[b0 + cbase + slot];
            float e = asr[(unsigned)(sn_l * H + hd)] + ad;
            e = e > 0.f ? e : 0.2f * e;
            p_l = __expf(fminf(e, 80.f));
        }
        const int nnG = (nn + G - 1) & ~(G - 1);
        for (int eb = 0; eb < nnG; eb += G)
            do_group(sn_l, p_l, eb);
    }

    const float inv_s = 1.f / ssum;
    #pragma unroll
    for (int v = 0; v < V; v++) acc[v] = fmaf(acc[v], inv_s, bv[v]);

    if constexpr (!LAST) {
        float lsum = 0.f, lsq = 0.f;
        #pragma unroll
        for (int v = 0; v < V; v++) { lsum += acc[v]; lsq = fmaf(acc[v], acc[v], lsq); }
        #pragma unroll
        for (int off = 1; off < 64; off <<= 1) {
            lsum += __shfl_xor(lsum, off);
            lsq  += __shfl_xor(lsq,  off);
        }
        float mu  = lsum * (1.f / CT);
        float var = lsq  * (1.f / CT) - mu * mu;
        float rs  = rsqrtf(var + 1e-5f);
        unsigned int od[ND];
        #pragma unroll
        for (int k = 0; k < ND; k++) {
            float y0 = (acc[2 * k]     - mu) * rs * gv[2 * k]     + bev[2 * k];
            float y1 = (acc[2 * k + 1] - mu) * rs * gv[2 * k + 1] + bev[2 * k + 1];
            y0 = y0 > 0.f ? y0 : expm1f(y0);
            y1 = y1 > 0.f ? y1 : expm1f(y1);
            od[k] = (unsigned int)f2u(y0) | ((unsigned int)f2u(y1) << 16);
        }
        unsigned int* ob = (unsigned int*)outv + (size_t)n * STR + coff;
        if constexpr (ND == 2) *(uint2*)ob = make_uint2(od[0], od[1]);
        else                   *ob = od[0];
    } else {
        if (flags[0]) {
            unsigned int o = (unsigned int)f2u(acc[0]) | ((unsigned int)f2u(acc[1]) << 16);
            *((unsigned int*)outv + (size_t)n * STR + coff) = o;
        } else {
            *(float2*)((float*)outv + (size_t)n * CT + V * l) = make_float2(acc[0], acc[1]);
        }
    }
}

// --------------------------------- launcher --------------------------------
extern "C" void kernel_launch(void* const* d_in, const int* in_sizes, int n_in,
                              void* d_out, int out_size, void* d_ws, size_t ws_size,
                              hipStream_t stream) {
    const void* x  = d_in[0];
    const void* ei = d_in[1];

    char* ws = (char*)d_ws;
    unsigned short* xp = (unsigned short*)(ws);     // [N,256] f16 = 25,600,000 B
    bf16*  hbuf   = (bf16*)(ws + 25600000);         // [N,256] bf16; also hosts xb
    // ---- contiguous zero region: counts, (pad), asr/adst x3 ----
    int*   counts = (int*)  (ws + 51200000);        //   200,000
    //     (pad)            (ws + 51400000)         //     4,096 (unused)
    float* asr1   = (float*)(ws + 51404096);        //   800,000
    float* adst1  = (float*)(ws + 52204096);        //   800,000
    float* asr2   = (float*)(ws + 53004096);        //   400,000
    float* adst2  = (float*)(ws + 53404096);        //   400,000
    float* asr3   = (float*)(ws + 53804096);        //   200,000
    float* adst3  = (float*)(ws + 54004096);        //   200,000
    const int kZeroInts = (54204096 - 51200000) / 4;  // 751,024 ints
    // ---- rest ----
    int*   scannd = (int*)  (ws + 54204096);        //   200,000
    int*   part   = (int*)  (ws + 54404096);        //       256
    int*   rowptr = (int*)  (ws + 54404352);        //   200,064
    int*   cursor = (int*)  (ws + 54604416);        //   200,000
    int*   csrsrc = (int*)  (ws + 54804416);        // 3,400,000
    int*   flags  = (int*)  (ws + 58404416);        //        64
    bf16*  Wt1    = (bf16*) (ws + 58404480);        //    65,536
    bf16*  Wt2    = (bf16*) (ws + 58470016);        //    65,536
    bf16*  Wt3    = (bf16*) (ws + 58535552);        //    32,768
    float* params = (float*)(ws + 58568320);        //     9,216

    bf16* xb = hbuf;

    const int nb_scan = (N_NODES + SCAN_B - 1) / SCAN_B;
    const int AGGB    = (N_NODES + 3) / 4;          // 12500 blocks, 1 node/wave
    const int n4      = N_NODES * 128 / 4;

    k_init<<<(kZeroInts + 255) / 256, 256, 0, stream>>>((const unsigned int*)x,
                                                        (const unsigned int*)ei,
                                                        counts, kZeroInts, flags);

    // CSR build
    k_hist  <<<(E_TOT + 255) / 256, 256, 0, stream>>>(flags, ei, counts);
    k_scan1 <<<nb_scan, SCAN_B, 0, stream>>>(counts, scannd, part, N_NODES);
    k_scan3 <<<(N_NODES + 255) / 256, 256, 0, stream>>>(counts, scannd, part, rowptr, cursor, N_NODES);
    k_scatter<<<(E_TOT + 255) / 256, 256, 0, stream>>>(flags, ei, cursor, csrsrc);

    // canonicalize all inputs in ONE dispatch
    PrepArgs pa;
    const int srcs[13] = {3, 4, 5, 6, 7, 9, 10, 11, 12, 13, 15, 16, 17};
    const int offs[13] = {0, 256, 512, 768, 1024, 1280, 1408, 1536, 1664, 1792, 1920, 2048, 2176};
    const int lens[13] = {256, 256, 256, 256, 256, 128, 128, 128, 128, 128, 128, 128, 128};
    for (int i = 0; i < 13; i++) { pa.src[i] = d_in[srcs[i]]; pa.off[i] = offs[i]; pa.len[i] = lens[i]; }
    k_prep_misc<<<333 + (n4 + 255) / 256, 256, 0, stream>>>(flags, x, xb, n4,
                                                            d_in[2], d_in[8], d_in[14],
                                                            Wt1, Wt2, Wt3, pa, params);

    // ---- layer 1: in 128 -> xp [N,256], H=4
    k_gemm_mfma2<128, 256, 4, 4><<<768, 256, 0, stream>>>(xb, Wt1, xp, params + 0, params + 256, asr1, adst1);
    k_agg9<256, 4, false><<<AGGB, 256, 0, stream>>>(flags, xp, asr1, adst1, rowptr, csrsrc,
                                                    params + 512, params + 768, params + 1024, hbuf);

    // ---- layer 2: in 256 -> xp [N,128], H=2
    k_gemm_mfma2<256, 128, 2, 2><<<768, 256, 0, stream>>>(hbuf, Wt2, xp, params + 1280, params + 1408, asr2, adst2);
    k_agg9<128, 2, false><<<AGGB, 256, 0, stream>>>(flags, xp, asr2, adst2, rowptr, csrsrc,
                                                    params + 1536, params + 1664, params + 1792, hbuf);

    // ---- layer 3: in 128 -> xp [N,128], H=1; write d_out (runtime dtype)
    k_gemm_mfma2<128, 128, 2, 1><<<768, 256, 0, stream>>>(hbuf, Wt3, xp, params + 1920, params + 2048, asr3, adst3);
    k_agg9<128, 1, true><<<AGGB, 256, 0, stream>>>(flags, xp, asr3, adst3, rowptr, csrsrc,
                                                   params + 2176, nullptr, nullptr, d_out);
}

// Round 17
// 299.669 us; speedup vs baseline: 1.1744x; 1.1744x over previous
//
#include <hip/hip_runtime.h>
#include <hip/hip_bf16.h>
#include <hip/hip_fp16.h>
#include <math.h>

#define N_NODES 50000
#define N_EDGES 800000
#define E_TOT   850000   // N_EDGES + N_NODES self-loops
#define SCAN_B  1024

typedef __hip_bfloat16 bf16;
typedef __attribute__((ext_vector_type(8))) short short8v;   // 8 bf16 (4 VGPR)
typedef __attribute__((ext_vector_type(4))) float float4v;   // MFMA acc

static __device__ __forceinline__ float u2f(unsigned short u) {
    return __uint_as_float(((unsigned int)u) << 16);
}
static __device__ __forceinline__ unsigned short f2u(float f) {   // RNE f32->bf16
    unsigned int u = __float_as_uint(f);
    return (unsigned short)((u + 0x7FFFu + ((u >> 16) & 1u)) >> 16);
}
static __device__ __forceinline__ float ldr(const void* p, int i, bool bf) {
    return bf ? u2f(((const unsigned short*)p)[i]) : ((const float*)p)[i];
}

// ------------------ init: zero scratch + dtype detection -------------------
__global__ void k_init(const unsigned int* __restrict__ x32,
                       const unsigned int* __restrict__ ei32,
                       int* __restrict__ zero_base, int nzero,
                       int* __restrict__ flags) {
    int i = blockIdx.x * 256 + threadIdx.x;
    if (i < nzero) zero_base[i] = 0;
    if (blockIdx.x == 0) {
        __shared__ int c1, c2;
        if (threadIdx.x == 0) { c1 = 0; c2 = 0; }
        __syncthreads();
        unsigned int e = (x32[threadIdx.x] >> 7) & 0xFF;
        if (e >= 90 && e <= 140) atomicAdd(&c1, 1);
        if (threadIdx.x < 64 && ei32[2 * threadIdx.x + 1] == 0) atomicAdd(&c2, 1);
        __syncthreads();
        if (threadIdx.x == 0) {
            flags[0] = (c1 >= 128) ? 1 : 0;   // float inputs are bf16
            flags[1] = (c2 >= 48) ? 1 : 0;    // edge_index is int64
        }
    }
}

// ------------------------------ CSR build ---------------------------------
__global__ void k_hist(const int* __restrict__ flags, const void* __restrict__ ei,
                       int* __restrict__ counts) {
    int i = blockIdx.x * blockDim.x + threadIdx.x;
    if (i >= E_TOT) return;
    int d;
    if (i < N_EDGES)
        d = flags[1] ? (int)((const long long*)ei)[N_EDGES + i]
                     : ((const int*)ei)[N_EDGES + i];
    else
        d = i - N_EDGES;
    atomicAdd(&counts[d], 1);
}

__global__ void k_scan1(const int* __restrict__ counts, int* __restrict__ scanned,
                        int* __restrict__ partial, int n) {
    __shared__ int sh[SCAN_B];
    int i = blockIdx.x * SCAN_B + threadIdx.x;
    sh[threadIdx.x] = (i < n) ? counts[i] : 0;
    __syncthreads();
    for (int off = 1; off < SCAN_B; off <<= 1) {
        int t = (threadIdx.x >= off) ? sh[threadIdx.x - off] : 0;
        __syncthreads();
        sh[threadIdx.x] += t;
        __syncthreads();
    }
    if (i < n) scanned[i] = sh[threadIdx.x];
    if (threadIdx.x == SCAN_B - 1) partial[blockIdx.x] = sh[SCAN_B - 1];
}

// rowptr/cursor; per-block prefix of `partial` computed inline (j is
// block-uniform: 256-thread blocks align inside 1024-node scan tiles).
__global__ void k_scan3(const int* __restrict__ counts, const int* __restrict__ scanned,
                        const int* __restrict__ partial, int* __restrict__ rowptr,
                        int* __restrict__ cursor, int n) {
    __shared__ int base_sh;
    if (threadIdx.x == 0) {
        const int jmax = (blockIdx.x * 256) / SCAN_B;
        int acc = 0;
        for (int b = 0; b < jmax; b++) acc += partial[b];
        base_sh = acc;
    }
    __syncthreads();
    int i = blockIdx.x * 256 + threadIdx.x;
    if (i >= n) return;
    int incl = scanned[i] + base_sh;
    rowptr[i + 1] = incl;
    cursor[i]     = incl - counts[i];
    if (i == 0) rowptr[0] = 0;
}

__global__ void k_scatter(const int* __restrict__ flags, const void* __restrict__ ei,
                          int* __restrict__ cursor, int* __restrict__ csr_src) {
    int i = blockIdx.x * blockDim.x + threadIdx.x;
    if (i >= E_TOT) return;
    int s, d;
    if (i < N_EDGES) {
        if (flags[1]) {
            s = (int)((const long long*)ei)[i];
            d = (int)((const long long*)ei)[N_EDGES + i];
        } else {
            s = ((const int*)ei)[i];
            d = ((const int*)ei)[N_EDGES + i];
        }
    } else {
        s = d = i - N_EDGES;
    }
    int pos = atomicAdd(&cursor[d], 1);
    csr_src[pos] = s;
}

// --------------- canonicalization: x, weights, small params ----------------
struct PrepArgs { const void* src[13]; int off[13]; int len[13]; };

__global__ void k_prep_misc(const int* __restrict__ flags,
                            const void* __restrict__ x, bf16* __restrict__ xb, int n4,
                            const void* __restrict__ W1, const void* __restrict__ W2,
                            const void* __restrict__ W3,
                            bf16* __restrict__ Wt1, bf16* __restrict__ Wt2,
                            bf16* __restrict__ Wt3,
                            PrepArgs a, float* __restrict__ par) {
    const bool bf = flags[0] != 0;
    const int b = blockIdx.x;
    if (b < 320) {
        int i = b * 256 + threadIdx.x;
        if (i < 32768) {                       // W1 [128][256] -> Wt1 [256][128]
            int k = i >> 8, c = i & 255;
            Wt1[c * 128 + k] = __float2bfloat16(ldr(W1, i, bf));
        } else if (i < 65536) {                // W2 [256][128] -> Wt2 [128][256]
            int j = i - 32768, k = j >> 7, c = j & 127;
            Wt2[c * 256 + k] = __float2bfloat16(ldr(W2, j, bf));
        } else if (i < 81920) {                // W3 [128][128] -> Wt3 [128][128]
            int j = i - 65536, k = j >> 7, c = j & 127;
            Wt3[c * 128 + k] = __float2bfloat16(ldr(W3, j, bf));
        }
    } else if (b < 333) {
        int seg = b - 320;                     // 13 segments
        for (int i = threadIdx.x; i < a.len[seg]; i += blockDim.x)
            par[a.off[seg] + i] = ldr(a.src[seg], i, bf);
    } else {
        int i = (b - 333) * 256 + threadIdx.x; // x -> bf16 (vec4)
        if (i < n4) {
            if (bf) {
                ((ushort4*)xb)[i] = ((const ushort4*)x)[i];
            } else {
                float4 f = ((const float4*)x)[i];
                ushort4 u;
                u.x = f2u(f.x); u.y = f2u(f.y); u.z = f2u(f.z); u.w = f2u(f.w);
                ((ushort4*)xb)[i] = u;
            }
        }
    }
}

// ------------- MFMA GEMM (swapped operands) + fused attention dots ---------
// A [M][K] bf16; Wt [NT][K] bf16; xp [M][NT] f16.
// When NSG==H each slice-group is the sole writer of its head's dots ->
// plain stores instead of atomics (asr buffers pre-zeroed anyway).
template<int K, int NT, int SPW, int H>
__global__ __launch_bounds__(256) void k_gemm_mfma2(const bf16* __restrict__ A,
                                                    const bf16* __restrict__ Wt,
                                                    unsigned short* __restrict__ xp,
                                                    const float* __restrict__ att_s,
                                                    const float* __restrict__ att_d,
                                                    float* __restrict__ asr,
                                                    float* __restrict__ adst) {
    constexpr int KF     = K / 32;
    constexpr int NSG    = NT / (16 * SPW);
    constexpr int NTILES = N_NODES / 16;
    constexpr int C      = NT / H;
    const int l    = threadIdx.x & 63;
    const int wid  = blockIdx.x * 4 + (threadIdx.x >> 6);
    const int sg   = wid % NSG;
    const int wpg  = (gridDim.x * 4) / NSG;
    const int t0   = wid / NSG;
    const int r16  = l & 15;
    const int kgrp = (l >> 4) * 8;
    const int head = (sg * SPW * 16) / C;

    short8v b[SPW][KF];
    float as_r[SPW][4], ad_r[SPW][4];
    #pragma unroll
    for (int s = 0; s < SPW; s++) {
        const int cs  = (sg * SPW + s) * 16;
        const int col = cs + r16;
        #pragma unroll
        for (int kf = 0; kf < KF; kf++)
            b[s][kf] = *(const short8v*)(Wt + (size_t)col * K + kf * 32 + kgrp);
        #pragma unroll
        for (int r = 0; r < 4; r++) {
            const int ch = cs + (l >> 4) * 4 + r;
            as_r[s][r] = att_s[ch];
            ad_r[s][r] = att_d[ch];
        }
    }

    for (int t = t0; t < NTILES; t += wpg) {
        const int m0 = t * 16;
        short8v a[KF];
        #pragma unroll
        for (int kf = 0; kf < KF; kf++)
            a[kf] = *(const short8v*)(A + (size_t)(m0 + r16) * K + kf * 32 + kgrp);
        float4v acc[SPW] = {};
        #pragma unroll
        for (int kf = 0; kf < KF; kf++)
            #pragma unroll
            for (int s = 0; s < SPW; s++)
                acc[s] = __builtin_amdgcn_mfma_f32_16x16x32_bf16(b[s][kf], a[kf], acc[s], 0, 0, 0);

        float pa = 0.f, pd = 0.f;
        #pragma unroll
        for (int s = 0; s < SPW; s++)
            #pragma unroll
            for (int r = 0; r < 4; r++) {
                pa = fmaf(acc[s][r], as_r[s][r], pa);
                pd = fmaf(acc[s][r], ad_r[s][r], pd);
            }
        pa += __shfl_xor(pa, 16); pa += __shfl_xor(pa, 32);
        pd += __shfl_xor(pd, 16); pd += __shfl_xor(pd, 32);
        if (l < 16) {
            if constexpr (NSG == H) {
                asr [(size_t)(m0 + l) * H + head] = pa;
                adst[(size_t)(m0 + l) * H + head] = pd;
            } else {
                atomicAdd(&asr [(size_t)(m0 + l) * H + head], pa);
                atomicAdd(&adst[(size_t)(m0 + l) * H + head], pd);
            }
        }

        const int node = m0 + r16;
        #pragma unroll
        for (int s = 0; s < SPW; s++) {
            const int ch = (sg * SPW + s) * 16 + (l >> 4) * 4;
            uint2 o;
            o.x = (unsigned int)__half_as_ushort(__float2half(acc[s][0])) |
                  ((unsigned int)__half_as_ushort(__float2half(acc[s][1])) << 16);
            o.y = (unsigned int)__half_as_ushort(__float2half(acc[s][2])) |
                  ((unsigned int)__half_as_ushort(__float2half(acc[s][3])) << 16);
            *(uint2*)(xp + (size_t)node * NT + ch) = o;
        }
    }
}

// ---- SINGLE-PASS edge-softmax + aggregation + bias (+ LayerNorm + ELU) ----
// Defer-max: logits are bounded (sigma~1.2; clamp at 80 guards fp32 exp), so
// accumulate unnormalized p=exp(e) and s=sum(p) in ONE pass, divide at end.
// s is replicated across the head group via the shfl broadcast -> NO reduce,
// NO dependent-gather prologue. ONE node per full wave, RUNTIME group loop
// (G=4/8 keeps live gather state ~16 regs; 28 VGPR / ~71% occupancy is the
// measured optimum — deeper unroll regressed twice: r13 44VGPR, r16 72VGPR).
// v_fma_mix unpack, 32-bit offsets. f16 xp.
template<int CT, int H, bool LAST>
__global__ __launch_bounds__(256) void k_agg8(const int* __restrict__ flags,
                                              const unsigned short* __restrict__ xp,
                                              const float* __restrict__ asr,
                                              const float* __restrict__ adst,
                                              const int* __restrict__ rowptr,
                                              const int* __restrict__ csr_src,
                                              const float* __restrict__ bias,
                                              const float* __restrict__ gamma,
                                              const float* __restrict__ beta,
                                              void* __restrict__ outv) {
    constexpr int V   = CT / 64;      // channels per lane (4 or 2)
    constexpr int C   = CT / H;
    constexpr int LPH = C / V;        // lanes per head group (16/32/64)
    constexpr int ND  = V / 2;        // dwords gathered per lane (2 or 1)
    constexpr int STR = CT / 2;       // xp row stride in dwords (pow2)
    constexpr int G   = (ND == 2) ? 4 : 8;   // gather depth (register-budgeted)
    const int l     = threadIdx.x & 63;
    const int w     = threadIdx.x >> 6;
    const int hd    = l / LPH;
    const int slot  = l & (LPH - 1);
    const int lbase = hd * LPH;
    const unsigned int coff = ND * l;

    float bv[V], gv[V], bev[V];
    #pragma unroll
    for (int v = 0; v < V; v++) bv[v] = bias[V * l + v];
    if constexpr (!LAST) {
        #pragma unroll
        for (int v = 0; v < V; v++) {
            gv[v]  = gamma[V * l + v];
            bev[v] = beta [V * l + v];
        }
    }
    const unsigned int* xpd = (const unsigned int*)xp;

    const int n = blockIdx.x * 4 + w;
    if (n >= N_NODES) return;
    const int b0 = rowptr[n], b1 = rowptr[n + 1];
    const int deg = b1 - b0;
    const float ad = adst[n * H + hd];
    const int sn_first = csr_src[b0];

    float ssum = 0.f;
    float acc[V];
    #pragma unroll
    for (int v = 0; v < V; v++) acc[v] = 0.f;

    // single pass: LPH-edge chunks; slot lane computes p=exp(e); whole wave
    // gathers G-deep with p broadcast; pad lanes carry p=0 (gather harmless).
    for (int cbase = 0; cbase < deg; cbase += LPH) {
        const int nn = min(LPH, deg - cbase);
        int   sn_l = sn_first;
        float p_l  = 0.f;
        if (slot < nn) {
            sn_l = csr_src[b0 + cbase + slot];
            float e = asr[(unsigned)(sn_l * H + hd)] + ad;
            e = e > 0.f ? e : 0.2f * e;
            p_l = __expf(fminf(e, 80.f));
        }
        const int nnG = (nn + G - 1) & ~(G - 1);
        for (int eb = 0; eb < nnG; eb += G) {
            unsigned int offs[G]; float ps[G];
            #pragma unroll
            for (int g = 0; g < G; g++) {
                int sn = __shfl(sn_l, lbase + eb + g);
                ps[g]  = __shfl(p_l,  lbase + eb + g);
                offs[g] = (unsigned int)sn * STR + coff;   // 32-bit offsets
            }
            unsigned int d[G][ND];
            #pragma unroll
            for (int g = 0; g < G; g++) {
                if constexpr (ND == 2)
                    *(uint2*)d[g] = *(const uint2*)(xpd + offs[g]);
                else
                    d[g][0] = xpd[offs[g]];
            }
            #pragma unroll
            for (int g = 0; g < G; g++) {
                ssum += ps[g];
                #pragma unroll
                for (int k = 0; k < ND; k++) {
                    __half2 h2 = *(__half2*)&d[g][k];      // -> v_fma_mix_f32
                    acc[2 * k]     = fmaf(ps[g], __low2float(h2),  acc[2 * k]);
                    acc[2 * k + 1] = fmaf(ps[g], __high2float(h2), acc[2 * k + 1]);
                }
            }
        }
    }
    const float inv_s = 1.f / ssum;
    #pragma unroll
    for (int v = 0; v < V; v++) acc[v] = fmaf(acc[v], inv_s, bv[v]);

    if constexpr (!LAST) {
        float lsum = 0.f, lsq = 0.f;
        #pragma unroll
        for (int v = 0; v < V; v++) { lsum += acc[v]; lsq = fmaf(acc[v], acc[v], lsq); }
        #pragma unroll
        for (int off = 1; off < 64; off <<= 1) {
            lsum += __shfl_xor(lsum, off);
            lsq  += __shfl_xor(lsq,  off);
        }
        float mu  = lsum * (1.f / CT);
        float var = lsq  * (1.f / CT) - mu * mu;
        float rs  = rsqrtf(var + 1e-5f);
        unsigned int od[ND];
        #pragma unroll
        for (int k = 0; k < ND; k++) {
            float y0 = (acc[2 * k]     - mu) * rs * gv[2 * k]     + bev[2 * k];
            float y1 = (acc[2 * k + 1] - mu) * rs * gv[2 * k + 1] + bev[2 * k + 1];
            y0 = y0 > 0.f ? y0 : expm1f(y0);
            y1 = y1 > 0.f ? y1 : expm1f(y1);
            od[k] = (unsigned int)f2u(y0) | ((unsigned int)f2u(y1) << 16);
        }
        unsigned int* ob = (unsigned int*)outv + (size_t)n * STR + coff;
        if constexpr (ND == 2) *(uint2*)ob = make_uint2(od[0], od[1]);
        else                   *ob = od[0];
    } else {
        if (flags[0]) {
            unsigned int o = (unsigned int)f2u(acc[0]) | ((unsigned int)f2u(acc[1]) << 16);
            *((unsigned int*)outv + (size_t)n * STR + coff) = o;
        } else {
            *(float2*)((float*)outv + (size_t)n * CT + V * l) = make_float2(acc[0], acc[1]);
        }
    }
}

// --------------------------------- launcher --------------------------------
extern "C" void kernel_launch(void* const* d_in, const int* in_sizes, int n_in,
                              void* d_out, int out_size, void* d_ws, size_t ws_size,
                              hipStream_t stream) {
    const void* x  = d_in[0];
    const void* ei = d_in[1];

    char* ws = (char*)d_ws;
    unsigned short* xp = (unsigned short*)(ws);     // [N,256] f16 = 25,600,000 B
    bf16*  hbuf   = (bf16*)(ws + 25600000);         // [N,256] bf16; also hosts xb
    // ---- contiguous zero region: counts, (pad), asr/adst x3 ----
    int*   counts = (int*)  (ws + 51200000);        //   200,000
    //     (pad)            (ws + 51400000)         //     4,096 (unused)
    float* asr1   = (float*)(ws + 51404096);        //   800,000
    float* adst1  = (float*)(ws + 52204096);        //   800,000
    float* asr2   = (float*)(ws + 53004096);        //   400,000
    float* adst2  = (float*)(ws + 53404096);        //   400,000
    float* asr3   = (float*)(ws + 53804096);        //   200,000
    float* adst3  = (float*)(ws + 54004096);        //   200,000
    const int kZeroInts = (54204096 - 51200000) / 4;  // 751,024 ints
    // ---- rest ----
    int*   scannd = (int*)  (ws + 54204096);        //   200,000
    int*   part   = (int*)  (ws + 54404096);        //       256
    int*   rowptr = (int*)  (ws + 54404352);        //   200,064
    int*   cursor = (int*)  (ws + 54604416);        //   200,000
    int*   csrsrc = (int*)  (ws + 54804416);        // 3,400,000
    int*   flags  = (int*)  (ws + 58404416);        //        64
    bf16*  Wt1    = (bf16*) (ws + 58404480);        //    65,536
    bf16*  Wt2    = (bf16*) (ws + 58470016);        //    65,536
    bf16*  Wt3    = (bf16*) (ws + 58535552);        //    32,768
    float* params = (float*)(ws + 58568320);        //     9,216

    bf16* xb = hbuf;

    const int nb_scan = (N_NODES + SCAN_B - 1) / SCAN_B;
    const int AGGB    = (N_NODES + 3) / 4;          // 12500 blocks, 1 node/wave
    const int n4      = N_NODES * 128 / 4;

    k_init<<<(kZeroInts + 255) / 256, 256, 0, stream>>>((const unsigned int*)x,
                                                        (const unsigned int*)ei,
                                                        counts, kZeroInts, flags);

    // CSR build
    k_hist  <<<(E_TOT + 255) / 256, 256, 0, stream>>>(flags, ei, counts);
    k_scan1 <<<nb_scan, SCAN_B, 0, stream>>>(counts, scannd, part, N_NODES);
    k_scan3 <<<(N_NODES + 255) / 256, 256, 0, stream>>>(counts, scannd, part, rowptr, cursor, N_NODES);
    k_scatter<<<(E_TOT + 255) / 256, 256, 0, stream>>>(flags, ei, cursor, csrsrc);

    // canonicalize all inputs in ONE dispatch
    PrepArgs pa;
    const int srcs[13] = {3, 4, 5, 6, 7, 9, 10, 11, 12, 13, 15, 16, 17};
    const int offs[13] = {0, 256, 512, 768, 1024, 1280, 1408, 1536, 1664, 1792, 1920, 2048, 2176};
    const int lens[13] = {256, 256, 256, 256, 256, 128, 128, 128, 128, 128, 128, 128, 128};
    for (int i = 0; i < 13; i++) { pa.src[i] = d_in[srcs[i]]; pa.off[i] = offs[i]; pa.len[i] = lens[i]; }
    k_prep_misc<<<333 + (n4 + 255) / 256, 256, 0, stream>>>(flags, x, xb, n4,
                                                            d_in[2], d_in[8], d_in[14],
                                                            Wt1, Wt2, Wt3, pa, params);

    // ---- layer 1: in 128 -> xp [N,256], H=4
    k_gemm_mfma2<128, 256, 4, 4><<<768, 256, 0, stream>>>(xb, Wt1, xp, params + 0, params + 256, asr1, adst1);
    k_agg8<256, 4, false><<<AGGB, 256, 0, stream>>>(flags, xp, asr1, adst1, rowptr, csrsrc,
                                                    params + 512, params + 768, params + 1024, hbuf);

    // ---- layer 2: in 256 -> xp [N,128], H=2
    k_gemm_mfma2<256, 128, 2, 2><<<768, 256, 0, stream>>>(hbuf, Wt2, xp, params + 1280, params + 1408, asr2, adst2);
    k_agg8<128, 2, false><<<AGGB, 256, 0, stream>>>(flags, xp, asr2, adst2, rowptr, csrsrc,
                                                    params + 1536, params + 1664, params + 1792, hbuf);

    // ---- layer 3: in 128 -> xp [N,128], H=1; write d_out (runtime dtype)
    k_gemm_mfma2<128, 128, 2, 1><<<768, 256, 0, stream>>>(hbuf, Wt3, xp, params + 1920, params + 2048, asr3, adst3);
    k_agg8<128, 1, true><<<AGGB, 256, 0, stream>>>(flags, xp, asr3, adst3, rowptr, csrsrc,
                                                   params + 2176, nullptr, nullptr, d_out);
}